// Round 2
// baseline (231.981 us; speedup 1.0000x reference)
//
#include <hip/hip_runtime.h>

// BidirectionalCrossAttention on gfx950.
// fp16 MFMA pipeline: LN -> 4x GEMM (QK/V proj, V pre-transposed) ->
// bidirectional flash attention (no-max base-2 softmax, l via ones-fragment MFMA)
// -> 2x GEMM (+bias) to fp32 output.
// R2: flash 3->2 barriers/jt + register prefetch; ones-col from reg constant;
// swapped-operand epilogues for vectorized stores everywhere; gemm_out 512 blocks.

typedef _Float16 half_t;
typedef __attribute__((ext_vector_type(4))) _Float16 half4v;
typedef __attribute__((ext_vector_type(8))) _Float16 half8v;
typedef __attribute__((ext_vector_type(4))) float floatx4;

#define MFMA16(a, b, c) __builtin_amdgcn_mfma_f32_16x16x32_f16((a), (b), (c), 0, 0, 0)

#if defined(__has_builtin)
#if __has_builtin(__builtin_amdgcn_exp2f)
#define EXP2F(x) __builtin_amdgcn_exp2f(x)
#else
#define EXP2F(x) exp2f(x)
#endif
#else
#define EXP2F(x) exp2f(x)
#endif

// ---------------------------------------------------------------------------
// LayerNorm: 8192 rows (4096 x + 4096 context) of 512 fp32 -> fp16, one wave/row
// ---------------------------------------------------------------------------
__global__ __launch_bounds__(256) void ln_kernel(
    const float* __restrict__ x, const float* __restrict__ ctx,
    const float* __restrict__ gx, const float* __restrict__ bx,
    const float* __restrict__ gc, const float* __restrict__ bc,
    half_t* __restrict__ xn, half_t* __restrict__ cn)
{
    const int wave = threadIdx.x >> 6, lane = threadIdx.x & 63;
    const int row = blockIdx.x * 4 + wave;  // 0..8191
    const float *src, *g, *b;
    half_t* dst;
    if (row < 4096) {
        src = x + (size_t)row * 512; g = gx; b = bx; dst = xn + (size_t)row * 512;
    } else {
        const size_t r = (size_t)(row - 4096);
        src = ctx + r * 512; g = gc; b = bc; dst = cn + r * 512;
    }
    const float4 a0 = *(const float4*)(src + lane * 4);
    const float4 a1 = *(const float4*)(src + 256 + lane * 4);
    float s = a0.x + a0.y + a0.z + a0.w + a1.x + a1.y + a1.z + a1.w;
    float q = a0.x * a0.x + a0.y * a0.y + a0.z * a0.z + a0.w * a0.w +
              a1.x * a1.x + a1.y * a1.y + a1.z * a1.z + a1.w * a1.w;
#pragma unroll
    for (int m = 1; m < 64; m <<= 1) {
        s += __shfl_xor(s, m);
        q += __shfl_xor(q, m);
    }
    const float mean = s * (1.0f / 512.0f);
    const float var = q * (1.0f / 512.0f) - mean * mean;
    const float rs = rsqrtf(var + 1e-5f);
    const float4 g0 = *(const float4*)(g + lane * 4);
    const float4 g1 = *(const float4*)(g + 256 + lane * 4);
    const float4 b0 = *(const float4*)(b + lane * 4);
    const float4 b1 = *(const float4*)(b + 256 + lane * 4);
    half4v h0, h1;
    h0[0] = (half_t)((a0.x - mean) * rs * g0.x + b0.x);
    h0[1] = (half_t)((a0.y - mean) * rs * g0.y + b0.y);
    h0[2] = (half_t)((a0.z - mean) * rs * g0.z + b0.z);
    h0[3] = (half_t)((a0.w - mean) * rs * g0.w + b0.w);
    h1[0] = (half_t)((a1.x - mean) * rs * g1.x + b1.x);
    h1[1] = (half_t)((a1.y - mean) * rs * g1.y + b1.y);
    h1[2] = (half_t)((a1.z - mean) * rs * g1.z + b1.z);
    h1[3] = (half_t)((a1.w - mean) * rs * g1.w + b1.w);
    *(half4v*)(dst + lane * 4) = h0;
    *(half4v*)(dst + 256 + lane * 4) = h1;
}

// ---------------------------------------------------------------------------
// Input projections: C[4096,512] = A(half)[4096,512] @ W(fp32->half)[512,512]
// z: 0=qk 1=v_t 2=cqk 3=cv_t   (tr = z&1)
// normal (tr=0): swapped operands -> C^T in regs -> half4 stores along d
//   out[((bb*8+h)*2048+nn)*64 + dd]
// tr=1: natural operands -> half4 stores along n
//   out[((bb*8+h)*64+dd)*2048 + nn]
// ---------------------------------------------------------------------------
__global__ __launch_bounds__(256) void gemm_in_kernel(
    const half_t* __restrict__ xn, const half_t* __restrict__ cn,
    const float* __restrict__ Wqk, const float* __restrict__ Wv,
    const float* __restrict__ Wcqk, const float* __restrict__ Wcv,
    half_t* __restrict__ qk, half_t* __restrict__ v_t,
    half_t* __restrict__ cqk, half_t* __restrict__ cv_t)
{
    const half_t* A; const float* B; half_t* O;
    switch (blockIdx.z) {
        case 0:  A = xn; B = Wqk;  O = qk;   break;
        case 1:  A = xn; B = Wv;   O = v_t;  break;
        case 2:  A = cn; B = Wcqk; O = cqk;  break;
        default: A = cn; B = Wcv;  O = cv_t; break;
    }
    const int tr = blockIdx.z & 1;
    const int mt0 = blockIdx.x * 128;   // data rows
    const int nt0 = blockIdx.y * 128;   // weight cols

    __shared__ alignas(16) half_t As[128][40];
    __shared__ alignas(16) half_t Bs[128][40];

    const int tid = threadIdx.x;
    const int wave = tid >> 6, lane = tid & 63;
    const int wr = wave >> 1, wc = wave & 1;
    const int q4 = lane >> 4, c = lane & 15;

    const floatx4 z4 = {0.f, 0.f, 0.f, 0.f};
    floatx4 acc[4][4];
#pragma unroll
    for (int mt = 0; mt < 4; ++mt)
#pragma unroll
        for (int nt = 0; nt < 4; ++nt) acc[mt][nt] = z4;

    for (int kb = 0; kb < 16; ++kb) {
        const int k0 = kb * 32;
#pragma unroll
        for (int p = 0; p < 2; ++p) {  // A tile 128x32 halfs
            const int cidx = p * 256 + tid;
            const int row = cidx >> 2, kc = (cidx & 3) * 8;
            *(half8v*)&As[row][kc] = *(const half8v*)(A + (size_t)(mt0 + row) * 512 + k0 + kc);
        }
#pragma unroll
        for (int p = 0; p < 4; ++p) {  // B tile 32x128 fp32 -> Bs = B^T halfs
            const int cidx = p * 256 + tid;
            const int k = cidx >> 5, n0 = (cidx & 31) * 4;
            const float4 w = *(const float4*)(B + (size_t)(k0 + k) * 512 + nt0 + n0);
            Bs[n0 + 0][k] = (half_t)w.x;
            Bs[n0 + 1][k] = (half_t)w.y;
            Bs[n0 + 2][k] = (half_t)w.z;
            Bs[n0 + 3][k] = (half_t)w.w;
        }
        __syncthreads();
        half8v f1[4], f2[4];
#pragma unroll
        for (int i = 0; i < 4; ++i) {
            f1[i] = tr ? *(const half8v*)&As[wr * 64 + i * 16 + c][q4 * 8]
                       : *(const half8v*)&Bs[wr * 64 + i * 16 + c][q4 * 8];
            f2[i] = tr ? *(const half8v*)&Bs[wc * 64 + i * 16 + c][q4 * 8]
                       : *(const half8v*)&As[wc * 64 + i * 16 + c][q4 * 8];
        }
#pragma unroll
        for (int mt = 0; mt < 4; ++mt)
#pragma unroll
            for (int nt = 0; nt < 4; ++nt)
                acc[mt][nt] = MFMA16(f1[mt], f2[nt], acc[mt][nt]);
        __syncthreads();
    }

    const int bb = mt0 >> 11;       // batch
    const int nnb = mt0 & 2047;     // row base within batch
    if (tr) {
        // m = data rows (r contiguous along n of v_t), n = weight cols
#pragma unroll
        for (int mt = 0; mt < 4; ++mt) {
            const int row = nnb + wr * 64 + mt * 16 + q4 * 4;
#pragma unroll
            for (int nt = 0; nt < 4; ++nt) {
                const int col = nt0 + wc * 64 + nt * 16 + c;
                const int h = col >> 6, dd = col & 63;
                half4v pk;
                pk[0] = (half_t)acc[mt][nt][0];
                pk[1] = (half_t)acc[mt][nt][1];
                pk[2] = (half_t)acc[mt][nt][2];
                pk[3] = (half_t)acc[mt][nt][3];
                *(half4v*)(O + ((size_t)(bb * 8 + h) * 64 + dd) * 2048 + row) = pk;
            }
        }
    } else {
        // m = weight cols (r contiguous along d of qk), n = data rows
#pragma unroll
        for (int mt = 0; mt < 4; ++mt) {
            const int colw = nt0 + wr * 64 + mt * 16 + q4 * 4;
            const int h = colw >> 6, dd = colw & 63;
#pragma unroll
            for (int nt = 0; nt < 4; ++nt) {
                const int row = nnb + wc * 64 + nt * 16 + c;
                half4v pk;
                pk[0] = (half_t)acc[mt][nt][0];
                pk[1] = (half_t)acc[mt][nt][1];
                pk[2] = (half_t)acc[mt][nt][2];
                pk[3] = (half_t)acc[mt][nt][3];
                *(half4v*)(O + ((size_t)(bb * 8 + h) * 2048 + row) * 64 + dd) = pk;
            }
        }
    }
}

// ---------------------------------------------------------------------------
// Bidirectional flash attention. grid (16 i-tiles, 16 bh, 2 dir), 256 thr.
// dir0: Q=qk K=cqk VT=cv_t -> out_h ; dir1: Q=cqk K=qk VT=v_t -> ctx_out_h
// 2 barriers/jt (P chunk is wave-private), K/V register prefetch,
// row-sum l via register ones-fragment, PV computed transposed (O^T) so the
// output epilogue packs half4 along d.
// ---------------------------------------------------------------------------
__global__ __launch_bounds__(256, 2) void flash_kernel(
    const half_t* __restrict__ qk, const half_t* __restrict__ cqk,
    const half_t* __restrict__ v_t, const half_t* __restrict__ cv_t,
    half_t* __restrict__ out_h, half_t* __restrict__ ctx_out_h)
{
    const int it = blockIdx.x, bh = blockIdx.y, dir = blockIdx.z;
    const half_t* Q  = dir ? cqk : qk;
    const half_t* K  = dir ? qk  : cqk;
    const half_t* VT = dir ? v_t : cv_t;
    half_t* Out = dir ? ctx_out_h : out_h;
    const half_t* Qb = Q + (size_t)bh * (2048 * 64);
    const half_t* Kb = K + (size_t)bh * (2048 * 64);
    const half_t* VTb = VT + (size_t)bh * (64 * 2048);

    __shared__ alignas(16) half_t Ks[128][72];    // 18432 B
    __shared__ alignas(16) half_t CVs[64][136];   // 17408 B
    __shared__ alignas(16) half_t Ps[128][72];    // 18432 B (64-col chunk, wave-private rows)

    const int tid = threadIdx.x;
    const int wave = tid >> 6, lane = tid & 63;
    const int q4 = lane >> 4, c = lane & 15;

    // ones fragment: A[m][k]=1 for m==0 -> row-sum row of O^T
    half8v onesb;
#pragma unroll
    for (int j = 0; j < 8; ++j) onesb[j] = (c == 0) ? (half_t)1.0f : (half_t)0.0f;

    // Q fragments, pre-scaled by SCALE*log2(e)
    half8v qf[2][2];
#pragma unroll
    for (int mt = 0; mt < 2; ++mt)
#pragma unroll
        for (int kt = 0; kt < 2; ++kt) {
            half8v v = *(const half8v*)(Qb + (size_t)(it * 128 + wave * 32 + mt * 16 + c) * 64 +
                                        kt * 32 + q4 * 8);
            qf[mt][kt] = v * (half_t)0.18033688f;
        }

    const floatx4 z4 = {0.f, 0.f, 0.f, 0.f};
    floatx4 accT[4][2];   // O^T accum: [vt d-tiles][mt row-tiles]
    floatx4 accL[2];      // row-sum l (row 0 of ones-tile)
#pragma unroll
    for (int vt = 0; vt < 4; ++vt)
#pragma unroll
        for (int mt = 0; mt < 2; ++mt) accT[vt][mt] = z4;
    accL[0] = z4; accL[1] = z4;

    // prefetch jt=0
    half8v kpre[4], vpre[4];
#pragma unroll
    for (int p = 0; p < 4; ++p) {
        const int cidx = p * 256 + tid;
        kpre[p] = *(const half8v*)(Kb + (size_t)(cidx >> 3) * 64 + (cidx & 7) * 8);
        vpre[p] = *(const half8v*)(VTb + (size_t)(cidx >> 4) * 2048 + (cidx & 15) * 8);
    }

    for (int jt = 0; jt < 16; ++jt) {
        __syncthreads();  // all waves done reading Ks/CVs of previous tile
#pragma unroll
        for (int p = 0; p < 4; ++p) {
            const int cidx = p * 256 + tid;
            *(half8v*)&Ks[cidx >> 3][(cidx & 7) * 8] = kpre[p];
            *(half8v*)&CVs[cidx >> 4][(cidx & 15) * 8] = vpre[p];
        }
        __syncthreads();  // staged tile visible
        if (jt < 15) {    // prefetch next tile; overlaps the whole compute phase
            const half_t* Kt = Kb + (size_t)(jt + 1) * 8192;
            const half_t* Vt = VTb + (jt + 1) * 128;
#pragma unroll
            for (int p = 0; p < 4; ++p) {
                const int cidx = p * 256 + tid;
                kpre[p] = *(const half8v*)(Kt + (size_t)(cidx >> 3) * 64 + (cidx & 7) * 8);
                vpre[p] = *(const half8v*)(Vt + (size_t)(cidx >> 4) * 2048 + (cidx & 15) * 8);
            }
        }

        // S strip: 32 rows x 128 cols per wave
        floatx4 s[2][8];
#pragma unroll
        for (int nt = 0; nt < 8; ++nt) {
            const half8v kf0 = *(const half8v*)&Ks[nt * 16 + c][q4 * 8];
            const half8v kf1 = *(const half8v*)&Ks[nt * 16 + c][32 + q4 * 8];
#pragma unroll
            for (int mt = 0; mt < 2; ++mt) {
                floatx4 t = MFMA16(qf[mt][0], kf0, z4);
                s[mt][nt] = MFMA16(qf[mt][1], kf1, t);
            }
        }

        // two 64-col chunks: exp -> wave-private Ps -> PV (no barriers needed)
#pragma unroll
        for (int ch = 0; ch < 2; ++ch) {
#pragma unroll
            for (int mt = 0; mt < 2; ++mt)
#pragma unroll
                for (int nl = 0; nl < 4; ++nl) {
                    const int nt = ch * 4 + nl;
#pragma unroll
                    for (int r = 0; r < 4; ++r) {
                        const float e = EXP2F(fminf(s[mt][nt][r], 15.0f));
                        Ps[wave * 32 + mt * 16 + q4 * 4 + r][nl * 16 + c] = (half_t)e;
                    }
                }
#pragma unroll
            for (int ktl = 0; ktl < 2; ++ktl) {
                half8v pf[2];  // serves as B-fragment of P^T (same read pattern as A)
#pragma unroll
                for (int mt = 0; mt < 2; ++mt)
                    pf[mt] = *(const half8v*)&Ps[wave * 32 + mt * 16 + c][ktl * 32 + q4 * 8];
#pragma unroll
                for (int vt = 0; vt < 4; ++vt) {
                    const half8v bf = *(const half8v*)&CVs[vt * 16 + c][(ch * 2 + ktl) * 32 + q4 * 8];
#pragma unroll
                    for (int mt = 0; mt < 2; ++mt)
                        accT[vt][mt] = MFMA16(bf, pf[mt], accT[vt][mt]);  // O^T = CV * P^T
                }
#pragma unroll
                for (int mt = 0; mt < 2; ++mt)
                    accL[mt] = MFMA16(onesb, pf[mt], accL[mt]);           // l row
            }
        }
    }

    // epilogue: O^T layout: m-local = d (q4*4+r), n-local = row (c); half4 along d
    const size_t ob = (size_t)(bh >> 3) * 2048 * 512 + (size_t)(bh & 7) * 64;
#pragma unroll
    for (int mt = 0; mt < 2; ++mt) {
        const float l = __shfl(accL[mt][0], c);  // l[row c] lives in lane (q4=0, c), reg 0
        const float rl = 1.0f / l;
        const int row = it * 128 + wave * 32 + mt * 16 + c;
#pragma unroll
        for (int vt = 0; vt < 4; ++vt) {
            half4v pk;
            pk[0] = (half_t)(accT[vt][mt][0] * rl);
            pk[1] = (half_t)(accT[vt][mt][1] * rl);
            pk[2] = (half_t)(accT[vt][mt][2] * rl);
            pk[3] = (half_t)(accT[vt][mt][3] * rl);
            *(half4v*)(Out + ob + (size_t)row * 512 + vt * 16 + q4 * 4) = pk;
        }
    }
}

// ---------------------------------------------------------------------------
// Output projections: d_out = A(half)[4096,512] @ W + bias (fp32 out)
// Swapped operands -> C^T in regs -> float4 stores along the 512-col dim.
// 64-row data tiles: grid (64, 4, 2) = 512 blocks.
// ---------------------------------------------------------------------------
__global__ __launch_bounds__(256) void gemm_out_kernel(
    const half_t* __restrict__ out_h, const half_t* __restrict__ ctx_out_h,
    const float* __restrict__ Wout, const float* __restrict__ bout,
    const float* __restrict__ Wcout, const float* __restrict__ bcout,
    float* __restrict__ dout)
{
    const half_t* A; const float* B; const float* bias; float* O;
    if (blockIdx.z == 0) { A = out_h;     B = Wout;  bias = bout;  O = dout; }
    else                 { A = ctx_out_h; B = Wcout; bias = bcout; O = dout + 2097152; }

    const int mt0 = blockIdx.x * 64;    // data rows (64 per block)
    const int nt0 = blockIdx.y * 128;   // weight cols

    __shared__ alignas(16) half_t As[64][40];
    __shared__ alignas(16) half_t Bs[128][40];

    const int tid = threadIdx.x;
    const int wave = tid >> 6, lane = tid & 63;
    const int wr = wave >> 1, wc = wave & 1;
    const int q4 = lane >> 4, c = lane & 15;

    const floatx4 z4 = {0.f, 0.f, 0.f, 0.f};
    floatx4 acc[4][2];  // [weight m-tiles][data n-tiles]
#pragma unroll
    for (int mt = 0; mt < 4; ++mt)
#pragma unroll
        for (int nt = 0; nt < 2; ++nt) acc[mt][nt] = z4;

    for (int kb = 0; kb < 16; ++kb) {
        const int k0 = kb * 32;
        {   // A tile 64x32 halfs: 1 b128 per thread
            const int row = tid >> 2, kc = (tid & 3) * 8;
            *(half8v*)&As[row][kc] = *(const half8v*)(A + (size_t)(mt0 + row) * 512 + k0 + kc);
        }
#pragma unroll
        for (int p = 0; p < 4; ++p) {  // B tile 32x128 fp32 -> Bs = B^T halfs
            const int cidx = p * 256 + tid;
            const int k = cidx >> 5, n0 = (cidx & 31) * 4;
            const float4 w = *(const float4*)(B + (size_t)(k0 + k) * 512 + nt0 + n0);
            Bs[n0 + 0][k] = (half_t)w.x;
            Bs[n0 + 1][k] = (half_t)w.y;
            Bs[n0 + 2][k] = (half_t)w.z;
            Bs[n0 + 3][k] = (half_t)w.w;
        }
        __syncthreads();
        half8v f1[4], f2[2];
#pragma unroll
        for (int i = 0; i < 4; ++i)
            f1[i] = *(const half8v*)&Bs[wr * 64 + i * 16 + c][q4 * 8];
#pragma unroll
        for (int i = 0; i < 2; ++i)
            f2[i] = *(const half8v*)&As[wc * 32 + i * 16 + c][q4 * 8];
#pragma unroll
        for (int mt = 0; mt < 4; ++mt)
#pragma unroll
            for (int nt = 0; nt < 2; ++nt)
                acc[mt][nt] = MFMA16(f1[mt], f2[nt], acc[mt][nt]);
        __syncthreads();
    }

#pragma unroll
    for (int mt = 0; mt < 4; ++mt) {
        const int col = nt0 + wr * 64 + mt * 16 + q4 * 4;
        const float4 bv = *(const float4*)(bias + col);
#pragma unroll
        for (int nt = 0; nt < 2; ++nt) {
            const int row = mt0 + wc * 32 + nt * 16 + c;
            float4 o;
            o.x = acc[mt][nt][0] + bv.x;
            o.y = acc[mt][nt][1] + bv.y;
            o.z = acc[mt][nt][2] + bv.z;
            o.w = acc[mt][nt][3] + bv.w;
            *(float4*)(O + (size_t)row * 512 + col) = o;
        }
    }
}

// ---------------------------------------------------------------------------
extern "C" void kernel_launch(void* const* d_in, const int* in_sizes, int n_in,
                              void* d_out, int out_size, void* d_ws, size_t ws_size,
                              hipStream_t stream)
{
    (void)in_sizes; (void)n_in; (void)out_size; (void)ws_size;
    const float* x      = (const float*)d_in[0];
    const float* ctx    = (const float*)d_in[1];
    const float* g_x    = (const float*)d_in[2];
    const float* b_x    = (const float*)d_in[3];
    const float* g_c    = (const float*)d_in[4];
    const float* b_c    = (const float*)d_in[5];
    const float* W_qk   = (const float*)d_in[6];
    const float* W_cqk  = (const float*)d_in[7];
    const float* W_v    = (const float*)d_in[8];
    const float* W_cv   = (const float*)d_in[9];
    const float* W_out  = (const float*)d_in[10];
    const float* b_out  = (const float*)d_in[11];
    const float* W_cout = (const float*)d_in[12];
    const float* b_cout = (const float*)d_in[13];
    float* out = (float*)d_out;

    half_t* ws = (half_t*)d_ws;
    const size_t SEG = 2097152;  // 2*2048*512 elements
    half_t* xn        = ws;
    half_t* cn        = ws + 1 * SEG;
    half_t* qk        = ws + 2 * SEG;  // [b,h,n,d]
    half_t* cqk       = ws + 3 * SEG;  // [b,h,n,d]
    half_t* v_t       = ws + 4 * SEG;  // [b,h,d,n]
    half_t* cv_t      = ws + 5 * SEG;  // [b,h,d,n]
    half_t* out_h     = ws + 6 * SEG;  // [b,n,h*d]
    half_t* ctx_out_h = ws + 7 * SEG;  // [b,n,h*d]

    ln_kernel<<<2048, 256, 0, stream>>>(x, ctx, g_x, b_x, g_c, b_c, xn, cn);
    gemm_in_kernel<<<dim3(32, 4, 4), 256, 0, stream>>>(xn, cn, W_qk, W_v, W_cqk, W_cv,
                                                       qk, v_t, cqk, cv_t);
    flash_kernel<<<dim3(16, 16, 2), 256, 0, stream>>>(qk, cqk, v_t, cv_t, out_h, ctx_out_h);
    gemm_out_kernel<<<dim3(64, 4, 2), 256, 0, stream>>>(out_h, ctx_out_h, W_out, b_out,
                                                        W_cout, b_cout, out);
}

// Round 3
// 180.312 us; speedup vs baseline: 1.2866x; 1.2866x over previous
//
#include <hip/hip_runtime.h>

// BidirectionalCrossAttention on gfx950.
// R3: prep kernel (LN + weight fp32->fp16 transpose, fused). GEMMs rebuilt on
// the m97 pattern: global_load_lds width=16 staging, BK=64, XOR-swizzled LDS
// (chunk ^= row&7; legal since global side of global_load_lds is free).
// Flash unchanged from R2 except outputs go to the dead xn/cn segments,
// freeing segments 6-7 for fp16 weights (total ws stays 32 MB).

typedef _Float16 half_t;
typedef __attribute__((ext_vector_type(4))) _Float16 half4v;
typedef __attribute__((ext_vector_type(8))) _Float16 half8v;
typedef __attribute__((ext_vector_type(4))) float floatx4;

#define MFMA16(a, b, c) __builtin_amdgcn_mfma_f32_16x16x32_f16((a), (b), (c), 0, 0, 0)

#if defined(__has_builtin)
#if __has_builtin(__builtin_amdgcn_exp2f)
#define EXP2F(x) __builtin_amdgcn_exp2f(x)
#else
#define EXP2F(x) exp2f(x)
#endif
#else
#define EXP2F(x) exp2f(x)
#endif

__device__ __forceinline__ void gld16(const half_t* g, half_t* l) {
    __builtin_amdgcn_global_load_lds(
        (const __attribute__((address_space(1))) void*)g,
        (__attribute__((address_space(3))) void*)l, 16, 0, 0);
}

// ---------------------------------------------------------------------------
// prep: blocks 0..2047 = LayerNorm (4 rows each, wave per row);
//       blocks 2048..2143 = weight transpose fp32[512k][512n] -> fp16 Wt[n][k]
//       (6 matrices x 16 tiles of 128x128)
// ---------------------------------------------------------------------------
__global__ __launch_bounds__(256) void prep_kernel(
    const float* __restrict__ x, const float* __restrict__ ctx,
    const float* __restrict__ gx, const float* __restrict__ bx,
    const float* __restrict__ gc, const float* __restrict__ bc,
    half_t* __restrict__ xn, half_t* __restrict__ cn,
    const float* __restrict__ W0, const float* __restrict__ W1,
    const float* __restrict__ W2, const float* __restrict__ W3,
    const float* __restrict__ W4, const float* __restrict__ W5,
    half_t* __restrict__ Wt)
{
    __shared__ alignas(16) half_t Ts[128][136];
    const int blk = blockIdx.x;
    const int tid = threadIdx.x;
    const int wave = tid >> 6, lane = tid & 63;

    if (blk < 2048) {  // -------- LayerNorm path --------
        const int row = blk * 4 + wave;  // 0..8191
        const float *src, *g, *b;
        half_t* dst;
        if (row < 4096) {
            src = x + (size_t)row * 512; g = gx; b = bx; dst = xn + (size_t)row * 512;
        } else {
            const size_t r = (size_t)(row - 4096);
            src = ctx + r * 512; g = gc; b = bc; dst = cn + r * 512;
        }
        const float4 a0 = *(const float4*)(src + lane * 4);
        const float4 a1 = *(const float4*)(src + 256 + lane * 4);
        float s = a0.x + a0.y + a0.z + a0.w + a1.x + a1.y + a1.z + a1.w;
        float q = a0.x * a0.x + a0.y * a0.y + a0.z * a0.z + a0.w * a0.w +
                  a1.x * a1.x + a1.y * a1.y + a1.z * a1.z + a1.w * a1.w;
#pragma unroll
        for (int m = 1; m < 64; m <<= 1) {
            s += __shfl_xor(s, m);
            q += __shfl_xor(q, m);
        }
        const float mean = s * (1.0f / 512.0f);
        const float var = q * (1.0f / 512.0f) - mean * mean;
        const float rs = rsqrtf(var + 1e-5f);
        const float4 g0 = *(const float4*)(g + lane * 4);
        const float4 g1 = *(const float4*)(g + 256 + lane * 4);
        const float4 b0 = *(const float4*)(b + lane * 4);
        const float4 b1 = *(const float4*)(b + 256 + lane * 4);
        half4v h0, h1;
        h0[0] = (half_t)((a0.x - mean) * rs * g0.x + b0.x);
        h0[1] = (half_t)((a0.y - mean) * rs * g0.y + b0.y);
        h0[2] = (half_t)((a0.z - mean) * rs * g0.z + b0.z);
        h0[3] = (half_t)((a0.w - mean) * rs * g0.w + b0.w);
        h1[0] = (half_t)((a1.x - mean) * rs * g1.x + b1.x);
        h1[1] = (half_t)((a1.y - mean) * rs * g1.y + b1.y);
        h1[2] = (half_t)((a1.z - mean) * rs * g1.z + b1.z);
        h1[3] = (half_t)((a1.w - mean) * rs * g1.w + b1.w);
        *(half4v*)(dst + lane * 4) = h0;
        *(half4v*)(dst + 256 + lane * 4) = h1;
        return;
    }

    // -------- weight transpose path --------
    const int b2 = blk - 2048;          // 0..95
    const int mat = b2 >> 4, tile = b2 & 15;
    const float* src;
    switch (mat) {
        case 0: src = W0; break;
        case 1: src = W1; break;
        case 2: src = W2; break;
        case 3: src = W3; break;
        case 4: src = W4; break;
        default: src = W5; break;
    }
    const int tr0 = (tile >> 2) * 128;  // k base
    const int tc0 = (tile & 3) * 128;   // n base
#pragma unroll
    for (int p = 0; p < 16; ++p) {
        const int idx = p * 256 + tid;
        const int r = idx >> 5, c4 = (idx & 31) * 4;
        const float4 w = *(const float4*)(src + (size_t)(tr0 + r) * 512 + tc0 + c4);
        Ts[c4 + 0][r] = (half_t)w.x;
        Ts[c4 + 1][r] = (half_t)w.y;
        Ts[c4 + 2][r] = (half_t)w.z;
        Ts[c4 + 3][r] = (half_t)w.w;
    }
    __syncthreads();
    half_t* dst = Wt + (size_t)mat * 262144;
#pragma unroll
    for (int p = 0; p < 8; ++p) {
        const int idx = p * 256 + tid;
        const int row = idx >> 4, ch = (idx & 15) * 8;
        *(half8v*)(dst + (size_t)(tc0 + row) * 512 + tr0 + ch) = *(const half8v*)&Ts[row][ch];
    }
}

// ---------------------------------------------------------------------------
// Input projections: C[4096,512] = A(fp16)[4096,512] @ W ; W as Wt[n][k] fp16.
// m97 pattern: global_load_lds 16B staging, BK=64, XOR swizzle chunk^=(row&7).
// z: 0=qk 1=v_t 2=cqk 3=cv_t (tr=z&1); epilogues identical to R2 (verified).
// ---------------------------------------------------------------------------
__global__ __launch_bounds__(256) void gemm_in_kernel(
    const half_t* __restrict__ xn, const half_t* __restrict__ cn,
    const half_t* __restrict__ Wt,
    half_t* __restrict__ qk, half_t* __restrict__ v_t,
    half_t* __restrict__ cqk, half_t* __restrict__ cv_t)
{
    const half_t* A; const half_t* B; half_t* O;
    switch (blockIdx.z) {
        case 0:  A = xn; B = Wt;          O = qk;   break;
        case 1:  A = xn; B = Wt + 262144; O = v_t;  break;
        case 2:  A = cn; B = Wt + 524288; O = cqk;  break;
        default: A = cn; B = Wt + 786432; O = cv_t; break;
    }
    const int tr = blockIdx.z & 1;
    const int mt0 = blockIdx.x * 128;   // data rows
    const int nt0 = blockIdx.y * 128;   // weight cols

    __shared__ alignas(16) half_t As[128 * 64];
    __shared__ alignas(16) half_t Ws[128 * 64];

    const int tid = threadIdx.x;
    const int wave = tid >> 6, lane = tid & 63;
    const int wr = wave >> 1, wc = wave & 1;
    const int q4 = lane >> 4, c = lane & 15;

    // staging geometry (kb-independent): issue p covers bytes [p*4096, +4096)
    int srow[4], scol[4];
#pragma unroll
    for (int p = 0; p < 4; ++p) {
        const int ofs = p * 4096 + wave * 1024 + lane * 16;  // bytes in tile
        const int row = ofs >> 7;
        const int pc = (ofs >> 4) & 7;
        srow[p] = row;
        scol[p] = (pc ^ (row & 7)) * 8;   // logical half offset this lane fetches
    }

    const half_t* P1 = tr ? As : Ws;   // m-operand tile
    const half_t* P2 = tr ? Ws : As;   // n-operand tile

    const floatx4 z4 = {0.f, 0.f, 0.f, 0.f};
    floatx4 acc[4][4];
#pragma unroll
    for (int mt = 0; mt < 4; ++mt)
#pragma unroll
        for (int nt = 0; nt < 4; ++nt) acc[mt][nt] = z4;

    for (int kb = 0; kb < 8; ++kb) {
        const int k0 = kb * 64;
#pragma unroll
        for (int p = 0; p < 4; ++p) {
            const int lofs = p * 2048 + wave * 512;  // halfs, wave-uniform
            gld16(A + (size_t)(mt0 + srow[p]) * 512 + k0 + scol[p], As + lofs);
            gld16(B + (size_t)(nt0 + srow[p]) * 512 + k0 + scol[p], Ws + lofs);
        }
        __syncthreads();
#pragma unroll
        for (int kt = 0; kt < 2; ++kt) {
            half8v f1[4], f2[4];
#pragma unroll
            for (int i = 0; i < 4; ++i) {
                const int r1 = wr * 64 + i * 16 + c;
                const int r2 = wc * 64 + i * 16 + c;
                f1[i] = *(const half8v*)&P1[(r1 << 6) + (((kt * 4 + q4) ^ (r1 & 7)) << 3)];
                f2[i] = *(const half8v*)&P2[(r2 << 6) + (((kt * 4 + q4) ^ (r2 & 7)) << 3)];
            }
#pragma unroll
            for (int mt = 0; mt < 4; ++mt)
#pragma unroll
                for (int nt = 0; nt < 4; ++nt)
                    acc[mt][nt] = MFMA16(f1[mt], f2[nt], acc[mt][nt]);
        }
        __syncthreads();
    }

    const int bb = mt0 >> 11;       // batch
    const int nnb = mt0 & 2047;     // row base within batch
    if (tr) {
        // m = data rows, n = weight cols; half4 along n of v_t
#pragma unroll
        for (int mt = 0; mt < 4; ++mt) {
            const int row = nnb + wr * 64 + mt * 16 + q4 * 4;
#pragma unroll
            for (int nt = 0; nt < 4; ++nt) {
                const int col = nt0 + wc * 64 + nt * 16 + c;
                const int h = col >> 6, dd = col & 63;
                half4v pk;
                pk[0] = (half_t)acc[mt][nt][0];
                pk[1] = (half_t)acc[mt][nt][1];
                pk[2] = (half_t)acc[mt][nt][2];
                pk[3] = (half_t)acc[mt][nt][3];
                *(half4v*)(O + ((size_t)(bb * 8 + h) * 64 + dd) * 2048 + row) = pk;
            }
        }
    } else {
        // m = weight cols, n = data rows; half4 along d of qk
#pragma unroll
        for (int mt = 0; mt < 4; ++mt) {
            const int colw = nt0 + wr * 64 + mt * 16 + q4 * 4;
            const int h = colw >> 6, dd = colw & 63;
#pragma unroll
            for (int nt = 0; nt < 4; ++nt) {
                const int row = nnb + wc * 64 + nt * 16 + c;
                half4v pk;
                pk[0] = (half_t)acc[mt][nt][0];
                pk[1] = (half_t)acc[mt][nt][1];
                pk[2] = (half_t)acc[mt][nt][2];
                pk[3] = (half_t)acc[mt][nt][3];
                *(half4v*)(O + ((size_t)(bb * 8 + h) * 2048 + row) * 64 + dd) = pk;
            }
        }
    }
}

// ---------------------------------------------------------------------------
// Bidirectional flash attention (unchanged from R2 except output pointers).
// ---------------------------------------------------------------------------
__global__ __launch_bounds__(256, 2) void flash_kernel(
    const half_t* __restrict__ qk, const half_t* __restrict__ cqk,
    const half_t* __restrict__ v_t, const half_t* __restrict__ cv_t,
    half_t* __restrict__ out_h, half_t* __restrict__ ctx_out_h)
{
    const int it = blockIdx.x, bh = blockIdx.y, dir = blockIdx.z;
    const half_t* Q  = dir ? cqk : qk;
    const half_t* K  = dir ? qk  : cqk;
    const half_t* VT = dir ? v_t : cv_t;
    half_t* Out = dir ? ctx_out_h : out_h;
    const half_t* Qb = Q + (size_t)bh * (2048 * 64);
    const half_t* Kb = K + (size_t)bh * (2048 * 64);
    const half_t* VTb = VT + (size_t)bh * (64 * 2048);

    __shared__ alignas(16) half_t Ks[128][72];
    __shared__ alignas(16) half_t CVs[64][136];
    __shared__ alignas(16) half_t Ps[128][72];

    const int tid = threadIdx.x;
    const int wave = tid >> 6, lane = tid & 63;
    const int q4 = lane >> 4, c = lane & 15;

    half8v onesb;
#pragma unroll
    for (int j = 0; j < 8; ++j) onesb[j] = (c == 0) ? (half_t)1.0f : (half_t)0.0f;

    half8v qf[2][2];
#pragma unroll
    for (int mt = 0; mt < 2; ++mt)
#pragma unroll
        for (int kt = 0; kt < 2; ++kt) {
            half8v v = *(const half8v*)(Qb + (size_t)(it * 128 + wave * 32 + mt * 16 + c) * 64 +
                                        kt * 32 + q4 * 8);
            qf[mt][kt] = v * (half_t)0.18033688f;
        }

    const floatx4 z4 = {0.f, 0.f, 0.f, 0.f};
    floatx4 accT[4][2];
    floatx4 accL[2];
#pragma unroll
    for (int vt = 0; vt < 4; ++vt)
#pragma unroll
        for (int mt = 0; mt < 2; ++mt) accT[vt][mt] = z4;
    accL[0] = z4; accL[1] = z4;

    half8v kpre[4], vpre[4];
#pragma unroll
    for (int p = 0; p < 4; ++p) {
        const int cidx = p * 256 + tid;
        kpre[p] = *(const half8v*)(Kb + (size_t)(cidx >> 3) * 64 + (cidx & 7) * 8);
        vpre[p] = *(const half8v*)(VTb + (size_t)(cidx >> 4) * 2048 + (cidx & 15) * 8);
    }

    for (int jt = 0; jt < 16; ++jt) {
        __syncthreads();
#pragma unroll
        for (int p = 0; p < 4; ++p) {
            const int cidx = p * 256 + tid;
            *(half8v*)&Ks[cidx >> 3][(cidx & 7) * 8] = kpre[p];
            *(half8v*)&CVs[cidx >> 4][(cidx & 15) * 8] = vpre[p];
        }
        __syncthreads();
        if (jt < 15) {
            const half_t* Kt = Kb + (size_t)(jt + 1) * 8192;
            const half_t* Vt = VTb + (jt + 1) * 128;
#pragma unroll
            for (int p = 0; p < 4; ++p) {
                const int cidx = p * 256 + tid;
                kpre[p] = *(const half8v*)(Kt + (size_t)(cidx >> 3) * 64 + (cidx & 7) * 8);
                vpre[p] = *(const half8v*)(Vt + (size_t)(cidx >> 4) * 2048 + (cidx & 15) * 8);
            }
        }

        floatx4 s[2][8];
#pragma unroll
        for (int nt = 0; nt < 8; ++nt) {
            const half8v kf0 = *(const half8v*)&Ks[nt * 16 + c][q4 * 8];
            const half8v kf1 = *(const half8v*)&Ks[nt * 16 + c][32 + q4 * 8];
#pragma unroll
            for (int mt = 0; mt < 2; ++mt) {
                floatx4 t = MFMA16(qf[mt][0], kf0, z4);
                s[mt][nt] = MFMA16(qf[mt][1], kf1, t);
            }
        }

#pragma unroll
        for (int ch = 0; ch < 2; ++ch) {
#pragma unroll
            for (int mt = 0; mt < 2; ++mt)
#pragma unroll
                for (int nl = 0; nl < 4; ++nl) {
                    const int nt = ch * 4 + nl;
#pragma unroll
                    for (int r = 0; r < 4; ++r) {
                        const float e = EXP2F(fminf(s[mt][nt][r], 15.0f));
                        Ps[wave * 32 + mt * 16 + q4 * 4 + r][nl * 16 + c] = (half_t)e;
                    }
                }
#pragma unroll
            for (int ktl = 0; ktl < 2; ++ktl) {
                half8v pf[2];
#pragma unroll
                for (int mt = 0; mt < 2; ++mt)
                    pf[mt] = *(const half8v*)&Ps[wave * 32 + mt * 16 + c][ktl * 32 + q4 * 8];
#pragma unroll
                for (int vt = 0; vt < 4; ++vt) {
                    const half8v bf = *(const half8v*)&CVs[vt * 16 + c][(ch * 2 + ktl) * 32 + q4 * 8];
#pragma unroll
                    for (int mt = 0; mt < 2; ++mt)
                        accT[vt][mt] = MFMA16(bf, pf[mt], accT[vt][mt]);
                }
#pragma unroll
                for (int mt = 0; mt < 2; ++mt)
                    accL[mt] = MFMA16(onesb, pf[mt], accL[mt]);
            }
        }
    }

    const size_t ob = (size_t)(bh >> 3) * 2048 * 512 + (size_t)(bh & 7) * 64;
#pragma unroll
    for (int mt = 0; mt < 2; ++mt) {
        const float l = __shfl(accL[mt][0], c);
        const float rl = 1.0f / l;
        const int row = it * 128 + wave * 32 + mt * 16 + c;
#pragma unroll
        for (int vt = 0; vt < 4; ++vt) {
            half4v pk;
            pk[0] = (half_t)(accT[vt][mt][0] * rl);
            pk[1] = (half_t)(accT[vt][mt][1] * rl);
            pk[2] = (half_t)(accT[vt][mt][2] * rl);
            pk[3] = (half_t)(accT[vt][mt][3] * rl);
            *(half4v*)(Out + ob + (size_t)row * 512 + vt * 16 + q4 * 4) = pk;
        }
    }
}

// ---------------------------------------------------------------------------
// Output projections: dout = A(fp16)[4096,512] @ W + bias (fp32).
// Same m97-style staging; swapped operands -> float4 stores along cols.
// ---------------------------------------------------------------------------
__global__ __launch_bounds__(256) void gemm_out_kernel(
    const half_t* __restrict__ out_h, const half_t* __restrict__ ctx_out_h,
    const half_t* __restrict__ Wt,
    const float* __restrict__ bout, const float* __restrict__ bcout,
    float* __restrict__ dout)
{
    const half_t* A; const half_t* B; const float* bias; float* O;
    if (blockIdx.z == 0) { A = out_h;     B = Wt + 1048576; bias = bout;  O = dout; }
    else                 { A = ctx_out_h; B = Wt + 1310720; bias = bcout; O = dout + 2097152; }

    const int mt0 = blockIdx.x * 64;    // data rows
    const int nt0 = blockIdx.y * 128;   // weight cols

    __shared__ alignas(16) half_t As[64 * 64];
    __shared__ alignas(16) half_t Ws[128 * 64];

    const int tid = threadIdx.x;
    const int wave = tid >> 6, lane = tid & 63;
    const int wr = wave >> 1, wc = wave & 1;
    const int q4 = lane >> 4, c = lane & 15;

    int srow[4], scol[4];
#pragma unroll
    for (int p = 0; p < 4; ++p) {
        const int ofs = p * 4096 + wave * 1024 + lane * 16;
        const int row = ofs >> 7;
        const int pc = (ofs >> 4) & 7;
        srow[p] = row;
        scol[p] = (pc ^ (row & 7)) * 8;
    }

    const floatx4 z4 = {0.f, 0.f, 0.f, 0.f};
    floatx4 acc[4][2];
#pragma unroll
    for (int mt = 0; mt < 4; ++mt)
#pragma unroll
        for (int nt = 0; nt < 2; ++nt) acc[mt][nt] = z4;

    for (int kb = 0; kb < 8; ++kb) {
        const int k0 = kb * 64;
#pragma unroll
        for (int p = 0; p < 4; ++p) {
            const int lofs = p * 2048 + wave * 512;
            gld16(B + (size_t)(nt0 + srow[p]) * 512 + k0 + scol[p], Ws + lofs);
            if (p < 2)
                gld16(A + (size_t)(mt0 + srow[p]) * 512 + k0 + scol[p], As + lofs);
        }
        __syncthreads();
#pragma unroll
        for (int kt = 0; kt < 2; ++kt) {
            half8v f1[4], f2[2];
#pragma unroll
            for (int i = 0; i < 4; ++i) {
                const int r1 = wr * 64 + i * 16 + c;
                f1[i] = *(const half8v*)&Ws[(r1 << 6) + (((kt * 4 + q4) ^ (r1 & 7)) << 3)];
            }
#pragma unroll
            for (int i = 0; i < 2; ++i) {
                const int r2 = wc * 32 + i * 16 + c;
                f2[i] = *(const half8v*)&As[(r2 << 6) + (((kt * 4 + q4) ^ (r2 & 7)) << 3)];
            }
#pragma unroll
            for (int mt = 0; mt < 4; ++mt)
#pragma unroll
                for (int nt = 0; nt < 2; ++nt)
                    acc[mt][nt] = MFMA16(f1[mt], f2[nt], acc[mt][nt]);
        }
        __syncthreads();
    }

#pragma unroll
    for (int mt = 0; mt < 4; ++mt) {
        const int col = nt0 + wr * 64 + mt * 16 + q4 * 4;
        const float4 bv = *(const float4*)(bias + col);
#pragma unroll
        for (int nt = 0; nt < 2; ++nt) {
            const int row = mt0 + wc * 32 + nt * 16 + c;
            float4 o;
            o.x = acc[mt][nt][0] + bv.x;
            o.y = acc[mt][nt][1] + bv.y;
            o.z = acc[mt][nt][2] + bv.z;
            o.w = acc[mt][nt][3] + bv.w;
            *(float4*)(O + (size_t)row * 512 + col) = o;
        }
    }
}

// ---------------------------------------------------------------------------
extern "C" void kernel_launch(void* const* d_in, const int* in_sizes, int n_in,
                              void* d_out, int out_size, void* d_ws, size_t ws_size,
                              hipStream_t stream)
{
    (void)in_sizes; (void)n_in; (void)out_size; (void)ws_size;
    const float* x      = (const float*)d_in[0];
    const float* ctx    = (const float*)d_in[1];
    const float* g_x    = (const float*)d_in[2];
    const float* b_x    = (const float*)d_in[3];
    const float* g_c    = (const float*)d_in[4];
    const float* b_c    = (const float*)d_in[5];
    const float* W_qk   = (const float*)d_in[6];
    const float* W_cqk  = (const float*)d_in[7];
    const float* W_v    = (const float*)d_in[8];
    const float* W_cv   = (const float*)d_in[9];
    const float* W_out  = (const float*)d_in[10];
    const float* b_out  = (const float*)d_in[11];
    const float* W_cout = (const float*)d_in[12];
    const float* b_cout = (const float*)d_in[13];
    float* out = (float*)d_out;

    half_t* ws = (half_t*)d_ws;
    const size_t SEG = 2097152;  // 2*2048*512 halfs = 4 MB
    half_t* xn        = ws;              // seg0: xn, later out_h
    half_t* cn        = ws + 1 * SEG;    // seg1: cn, later ctx_out_h
    half_t* qk        = ws + 2 * SEG;    // [b,h,n,d]
    half_t* cqk       = ws + 3 * SEG;    // [b,h,n,d]
    half_t* v_t       = ws + 4 * SEG;    // [b,h,d,n]
    half_t* cv_t      = ws + 5 * SEG;    // [b,h,d,n]
    half_t* Wt        = ws + 6 * SEG;    // 6 x 512x512 fp16 transposed weights
    half_t* out_h     = xn;              // flash overwrites dead xn
    half_t* ctx_out_h = cn;              // flash overwrites dead cn

    prep_kernel<<<2144, 256, 0, stream>>>(x, ctx, g_x, b_x, g_c, b_c, xn, cn,
                                          W_qk, W_v, W_cqk, W_cv, W_out, W_cout, Wt);
    gemm_in_kernel<<<dim3(32, 4, 4), 256, 0, stream>>>(xn, cn, Wt, qk, v_t, cqk, cv_t);
    flash_kernel<<<dim3(16, 16, 2), 256, 0, stream>>>(qk, cqk, v_t, cv_t, out_h, ctx_out_h);
    gemm_out_kernel<<<dim3(64, 4, 2), 256, 0, stream>>>(out_h, ctx_out_h, Wt, b_out, b_cout, out);
}